// Round 18
// baseline (7452.007 us; speedup 1.0000x reference)
//
#include <hip/hip_runtime.h>
#include <math.h>

#define HD   256
#define RB   4      // batch rows per block -> grid 512 = 2 blocks/CU possible
#define TB   1024   // 16 waves/block
#define TT   64
#define NST  32
#define BSZ  2048

typedef __attribute__((ext_vector_type(8))) short short8;
typedef __attribute__((ext_vector_type(4))) float f32x4;
typedef unsigned short ushort_t;

// ---------------- math helpers ----------------
__device__ __forceinline__ float sigmoidf_(float x) {
    return 1.0f / (1.0f + __expf(-x));
}
__device__ __forceinline__ float tanhf_(float x) {
    float e = __expf(2.0f * x);
    return 1.0f - 2.0f / (e + 1.0f);
}
__device__ __forceinline__ float seluf_(float x) {
    const float a = 1.6732632423543772f, s = 1.0507009873554805f;
    return x > 0.0f ? s * x : s * a * (__expf(x) - 1.0f);
}
__device__ __forceinline__ float erfinvf_(float x) {
    float w = -log1pf(-x * x);
    float p;
    if (w < 5.0f) {
        w -= 2.5f;
        p = 2.81022636e-08f;
        p = fmaf(p, w, 3.43273939e-07f);
        p = fmaf(p, w, -3.5233877e-06f);
        p = fmaf(p, w, -4.39150654e-06f);
        p = fmaf(p, w, 0.00021858087f);
        p = fmaf(p, w, -0.00125372503f);
        p = fmaf(p, w, -0.00417768164f);
        p = fmaf(p, w, 0.246640727f);
        p = fmaf(p, w, 1.50140941f);
    } else {
        w = sqrtf(w) - 3.0f;
        p = -0.000200214257f;
        p = fmaf(p, w, 0.000100950558f);
        p = fmaf(p, w, 0.00134934322f);
        p = fmaf(p, w, -0.00367342844f);
        p = fmaf(p, w, 0.00573950773f);
        p = fmaf(p, w, -0.0076224613f);
        p = fmaf(p, w, 0.00943887047f);
        p = fmaf(p, w, 1.00167406f);
        p = fmaf(p, w, 2.83297682f);
    }
    return p * x;
}

#define TF_ROUND(x0, x1, R) { x0 += x1; x1 = (x1 << (R)) | (x1 >> (32 - (R))); x1 ^= x0; }

__device__ __forceinline__ void threefry_(unsigned c0, unsigned c1, unsigned& r0, unsigned& r1) {
    const unsigned ks0 = 0u, ks1 = 42u, ks2 = 0x1BD11BDAu ^ 0u ^ 42u;
    unsigned x0 = c0 + ks0, x1 = c1 + ks1;
    TF_ROUND(x0,x1,13) TF_ROUND(x0,x1,15) TF_ROUND(x0,x1,26) TF_ROUND(x0,x1,6)
    x0 += ks1; x1 += ks2 + 1u;
    TF_ROUND(x0,x1,17) TF_ROUND(x0,x1,29) TF_ROUND(x0,x1,16) TF_ROUND(x0,x1,24)
    x0 += ks2; x1 += ks0 + 2u;
    TF_ROUND(x0,x1,13) TF_ROUND(x0,x1,15) TF_ROUND(x0,x1,26) TF_ROUND(x0,x1,6)
    x0 += ks0; x1 += ks1 + 3u;
    TF_ROUND(x0,x1,17) TF_ROUND(x0,x1,29) TF_ROUND(x0,x1,16) TF_ROUND(x0,x1,24)
    x0 += ks1; x1 += ks2 + 4u;
    TF_ROUND(x0,x1,13) TF_ROUND(x0,x1,15) TF_ROUND(x0,x1,26) TF_ROUND(x0,x1,6)
    x0 += ks2; x1 += ks0 + 5u;
    r0 = x0; r1 = x1;
}

// eps[i]: bits = o0 ^ o1 of threefry2x32(key(0,42), (0, i))  [verified round 5]
__device__ __forceinline__ float jax_normal_(unsigned i) {
    unsigned o0, o1;
    threefry_(0u, i, o0, o1);
    unsigned bits = o0 ^ o1;
    unsigned fb = (bits >> 9) | 0x3F800000u;
    float f = __uint_as_float(fb) - 1.0f;
    const float lo = -0.99999994f;
    float u = f * 2.0f + lo;
    u = fmaxf(lo, u);
    return 1.41421356237f * erfinvf_(u);
}

// fp32 <-> bf16
__device__ __forceinline__ ushort_t f2bf(float f) {
    unsigned u = __float_as_uint(f);
    return (ushort_t)((u + 0x7FFFu + ((u >> 16) & 1u)) >> 16);
}
__device__ __forceinline__ float bf2f(ushort_t u) {
    return __uint_as_float(((unsigned)u) << 16);
}

// swizzled bf16 mirror index (ushort units): row stride 256, 16B-chunk XOR swizzle
__device__ __forceinline__ int midx(int row, int k) {
    int chunk = k >> 3;
    return row * 256 + (((chunk ^ (row & 7)) << 3) | (k & 7));
}

// bf16 weight fragment load (WBF=1: from bf16 blob; else convert fp32 inline)
template<int WBF>
__device__ __forceinline__ short8 ldw(const ushort_t* __restrict__ Wbf,
                                      const float* __restrict__ Wf,
                                      int row, int k0) {
    if (WBF) {
        return *(const short8*)(Wbf + (size_t)row * 256 + k0);
    } else {
        const float4 w0 = *(const float4*)(Wf + (size_t)row * 256 + k0);
        const float4 w1 = *(const float4*)(Wf + (size_t)row * 256 + k0 + 4);
        union { ushort_t u[8]; short8 v; } bb;
        bb.u[0] = f2bf(w0.x); bb.u[1] = f2bf(w0.y); bb.u[2] = f2bf(w0.z); bb.u[3] = f2bf(w0.w);
        bb.u[4] = f2bf(w1.x); bb.u[5] = f2bf(w1.y); bb.u[6] = f2bf(w1.z); bb.u[7] = f2bf(w1.w);
        return bb.v;
    }
}

// MFMA 256->256 layer slice: inline B loads (low register pressure; TLP hides latency)
template<int WBF>
__device__ __forceinline__ f32x4 mfma_layer(const ushort_t* __restrict__ inbf,
                                            const ushort_t* __restrict__ Wbf,
                                            const float* __restrict__ Wf,
                                            const int lm, const int kb, const int jo)
{
    f32x4 acc = {0.f, 0.f, 0.f, 0.f};
#pragma unroll
    for (int kt = 0; kt < 8; ++kt) {
        const int k0 = kt * 32 + kb * 8;
        short8 a = *(const short8*)(inbf + midx(lm, k0));
        short8 b = ldw<WBF>(Wbf, Wf, jo, k0);
        acc = __builtin_amdgcn_mfma_f32_16x16x32_bf16(a, b, acc, 0, 0, 0);
    }
    return acc;
}

// ---------------- weight bf16 conversion prepass ----------------
// elements: [0,256K) O1..O4 | [256K,448K) Whh | [448K,512K) E1 | [512K,640K) E2
__global__ void cvt_k(const float* __restrict__ o1, const float* __restrict__ o2,
                      const float* __restrict__ o3, const float* __restrict__ o4,
                      const float* __restrict__ whh, const float* __restrict__ e1,
                      const float* __restrict__ e2, ushort_t* __restrict__ out) {
    int i = blockIdx.x * blockDim.x + threadIdx.x;
    if (i < 262144) {
        int m = i >> 16, r = i & 65535;
        const float* s = (m == 0) ? o1 : (m == 1) ? o2 : (m == 2) ? o3 : o4;
        out[i] = f2bf(s[r]);
    } else if (i < 458752) {
        out[i] = f2bf(whh[i - 262144]);
    } else if (i < 524288) {
        out[i] = f2bf(e1[i - 458752]);
    } else if (i < 655360) {
        out[i] = f2bf(e2[i - 524288]);
    }
}

// ---------------- fused pipeline kernel ----------------
// RB=4 -> grid 512 -> 2 blocks/CU (LDS ~57 KB, VGPR<=64 via launch_bounds(TB,8) with
// NO persistent B buffers -- inline loads keep arch demand ~45, no spill).
template<int WBF>
__global__ __launch_bounds__(TB, 8) void fused_kernel(
    const float* __restrict__ x,
    const float* __restrict__ meta,
    const float* __restrict__ W_ih,
    const float* __restrict__ W_hh,
    const float* __restrict__ b_ih,
    const float* __restrict__ b_hh,
    const float* __restrict__ eW1,
    const float* __restrict__ eb1,
    const float* __restrict__ eW2,
    const float* __restrict__ eb2,
    const float* __restrict__ oW1, const float* __restrict__ ob1,
    const float* __restrict__ oW2, const float* __restrict__ ob2,
    const float* __restrict__ oW3, const float* __restrict__ ob3,
    const float* __restrict__ oW4, const float* __restrict__ ob4,
    const float* __restrict__ outW,
    const float* __restrict__ outb,
    const ushort_t* __restrict__ wsbf,
    float* __restrict__ out)
{
    const int tid = threadIdx.x;
    const int t8  = tid & 255;
    // MFMA mapping
    const int l   = tid & 63;
    const int w   = tid >> 6;            // wave / n-tile base
    const int lm  = l & 15;              // A batch-row / B out-col within tile
    const int kb  = l >> 4;              // k-slice
    const int jo  = w * 16 + lm;         // owned output col (0..255)
    const bool act = (l < 16);           // lanes 0..15 hold rows 0..3 (reg r = row)
    const int b0  = blockIdx.x * RB;

    __shared__ float h0[RB][HD];                        // 4 KB fp32 h / y master
    __shared__ float xall[RB][TT * 4];                  // 4 KB
    __shared__ float red[TB];                           // 4 KB
    __shared__ __align__(16) ushort_t mir[4][16][256];  // 32 KB bf16 mirrors (rows 4-15 zero)
    __shared__ ushort_t kstb[6][RB * 256];              // 12 KB bf16 k-store
    __shared__ float meta_s[RB][4];
    __shared__ float dt_s[RB];
    // total ~56.3 KB -> 2 blocks/CU

    ushort_t* YBF = &mir[0][0][0];
    ushort_t* YTB = &mir[1][0][0];
    ushort_t* T1B = &mir[2][0][0];
    ushort_t* T2B = &mir[3][0][0];
    const ushort_t* wsO1  = wsbf;
    const ushort_t* wsO2  = wsbf + 65536;
    const ushort_t* wsO3  = wsbf + 131072;
    const ushort_t* wsO4  = wsbf + 196608;
    const ushort_t* wsWhh = wsbf + 262144;
    const ushort_t* wsE1  = wsbf + 458752;
    const ushort_t* wsE2  = wsbf + 524288;

    // ---- stage x, meta; zero h0 and mirrors ----
    {
        int r = tid >> 8, c = tid & 255;     // tid covers 4*256
        xall[r][c] = x[(size_t)(b0 + r) * 256 + c];
        h0[r][c] = 0.0f;
    }
    if (tid < RB * 4) { int r = tid >> 2, mm = tid & 3; meta_s[r][mm] = meta[(b0 + r) * 4 + mm]; }
    {
        unsigned* mz = (unsigned*)&mir[0][0][0];   // 8192 u32 = 32 KB
#pragma unroll
        for (int i = 0; i < 8; ++i) mz[tid + i * TB] = 0u;
    }
    __syncthreads();
    if (tid < RB) dt_s[tid] = (xall[tid][TT * 4 - 4] - xall[tid][0]) * (1.0f / (float)NST);

    // ---- GRU per-lane x-side constants for owned col jo ----
    float wxr[4], wxz[4], wxn[4];
#pragma unroll
    for (int d = 0; d < 4; ++d) {
        wxr[d] = W_ih[(size_t)jo * 8 + d];
        wxz[d] = W_ih[(size_t)(jo + 256) * 8 + d];
        wxn[d] = W_ih[(size_t)(jo + 512) * 8 + d];
    }
    float base_r[4], base_z[4], base_xn[4];
    {
        float mwr[4], mwz[4], mwn[4];
#pragma unroll
        for (int mm = 0; mm < 4; ++mm) {
            mwr[mm] = W_ih[(size_t)jo * 8 + 4 + mm];
            mwz[mm] = W_ih[(size_t)(jo + 256) * 8 + 4 + mm];
            mwn[mm] = W_ih[(size_t)(jo + 512) * 8 + 4 + mm];
        }
        const float bir = b_ih[jo], biz = b_ih[jo + 256], bin_ = b_ih[jo + 512];
        const float bhr = b_hh[jo], bhz = b_hh[jo + 256];
#pragma unroll
        for (int r = 0; r < 4; ++r) {        // row = r (RB=4)
            float sr = bir + bhr, sz = biz + bhz, sn = bin_;
#pragma unroll
            for (int mm = 0; mm < 4; ++mm) {
                float mv = meta_s[r][mm];
                sr = fmaf(mv, mwr[mm], sr);
                sz = fmaf(mv, mwz[mm], sz);
                sn = fmaf(mv, mwn[mm], sn);
            }
            base_r[r] = sr; base_z[r] = sz; base_xn[r] = sn;
        }
    }
    const float bhn = b_hh[512 + jo];

    // ---- GRU: 64 steps, MFMA bf16, mirror ping-pong, ONE barrier/step ----
    int p = 0;
#pragma unroll 1
    for (int t = 0; t < TT; ++t) {
        const ushort_t* YHp = &mir[p][0][0];
        f32x4 aR = {0.f,0.f,0.f,0.f}, aZ = {0.f,0.f,0.f,0.f}, aN = {0.f,0.f,0.f,0.f};
#pragma unroll 2
        for (int kt = 0; kt < 8; ++kt) {
            const int k0 = kt * 32 + kb * 8;
            short8 a = *(const short8*)(YHp + midx(lm, k0));
            short8 b = ldw<WBF>(wsWhh, W_hh, jo, k0);
            aR = __builtin_amdgcn_mfma_f32_16x16x32_bf16(a, b, aR, 0, 0, 0);
            b = ldw<WBF>(wsWhh, W_hh, jo + 256, k0);
            aZ = __builtin_amdgcn_mfma_f32_16x16x32_bf16(a, b, aZ, 0, 0, 0);
            b = ldw<WBF>(wsWhh, W_hh, jo + 512, k0);
            aN = __builtin_amdgcn_mfma_f32_16x16x32_bf16(a, b, aN, 0, 0, 0);
        }
        if (act) {
            ushort_t* YHn = &mir[p ^ 1][0][0];
#pragma unroll
            for (int r = 0; r < 4; ++r) {
                float xr = base_r[r], xz = base_z[r], xn = base_xn[r];
#pragma unroll
                for (int d = 0; d < 4; ++d) {
                    float xv = xall[r][t * 4 + d];
                    xr = fmaf(xv, wxr[d], xr);
                    xz = fmaf(xv, wxz[d], xz);
                    xn = fmaf(xv, wxn[d], xn);
                }
                float rg = sigmoidf_(xr + aR[r]);
                float zg = sigmoidf_(xz + aZ[r]);
                float ng = tanhf_(fmaf(rg, aN[r] + bhn, xn));
                float hp = h0[r][jo];
                float hnew = fmaf(zg, hp - ng, ng);
                h0[r][jo] = hnew;
                YHn[midx(r, jo)] = f2bf(hnew);
            }
        }
        __syncthreads();
        p ^= 1;
    }
    // final h bf16 in mir[0] (= YBF), fp32 in h0

    // ---- encoder (MFMA bf16): h1 = relu(h@E1+b1); mean/std; sample y0 ----
    {
        f32x4 acc = mfma_layer<WBF>(YBF, wsE1, eW1, lm, kb, jo);
        if (act) {
            const float eb1j = eb1[jo];
#pragma unroll
            for (int r = 0; r < 4; ++r)
                T1B[midx(r, jo)] = f2bf(fmaxf(acc[r] + eb1j, 0.0f));
        }
        __syncthreads();

        f32x4 aM = mfma_layer<WBF>(T1B, wsE2, eW2, lm, kb, jo);
        f32x4 aS = mfma_layer<WBF>(T1B, wsE2 + 65536, eW2 + 65536, lm, kb, jo);
        if (act) {
            const float bm = eb2[jo], bs = eb2[256 + jo];
#pragma unroll
            for (int r = 0; r < 4; ++r) {
                float e = jax_normal_((unsigned)((b0 + r) * HD + jo));
                float y0v = fmaf(e, aS[r] + bs, aM[r] + bm);
                h0[r][jo] = y0v;
                YBF[midx(r, jo)] = f2bf(y0v);
            }
        }
        __syncthreads();
    }

    // ---- dopri5: MFMA bf16 ODE; k's in bf16 LDS ----
    const float A21 = (float)(1.0/5.0);
    const float A31 = (float)(3.0/40.0),      A32 = (float)(9.0/40.0);
    const float A41 = (float)(44.0/45.0),     A42 = (float)(-56.0/15.0),    A43 = (float)(32.0/9.0);
    const float A51 = (float)(19372.0/6561.0),A52 = (float)(-25360.0/2187.0),
                A53 = (float)(64448.0/6561.0),A54 = (float)(-212.0/729.0);
    const float A61 = (float)(9017.0/3168.0), A62 = (float)(-355.0/33.0),
                A63 = (float)(46732.0/5247.0),A64 = (float)(49.0/176.0),    A65 = (float)(-5103.0/18656.0);
    const float B1f = (float)(35.0/384.0),    B3f = (float)(500.0/1113.0),  B4f = (float)(125.0/192.0),
                B5f = (float)(-2187.0/6784.0),B6f = (float)(11.0/84.0);

    const float o1b = ob1[jo], o2b = ob2[jo], o3b = ob3[jo], o4b = ob4[jo];
    float dtv[4];
    if (act) {
#pragma unroll
        for (int r = 0; r < 4; ++r) dtv[r] = dt_s[r];
    }

#pragma unroll 1
    for (int st = 0; st < NST; ++st) {
#pragma unroll 1
        for (int stage = 0; stage < 6; ++stage) {
            const ushort_t* in0 = (stage == 0) ? YBF : YTB;
            f32x4 acc = mfma_layer<WBF>(in0, wsO1, oW1, lm, kb, jo);
            if (act) {
#pragma unroll
                for (int r = 0; r < 4; ++r)
                    T1B[midx(r, jo)] = f2bf(seluf_(acc[r] + o1b));
            }
            __syncthreads();
            acc = mfma_layer<WBF>(T1B, wsO2, oW2, lm, kb, jo);
            if (act) {
#pragma unroll
                for (int r = 0; r < 4; ++r)
                    T2B[midx(r, jo)] = f2bf(seluf_(acc[r] + o2b));
            }
            __syncthreads();
            acc = mfma_layer<WBF>(T2B, wsO3, oW3, lm, kb, jo);
            if (act) {
#pragma unroll
                for (int r = 0; r < 4; ++r)
                    T1B[midx(r, jo)] = f2bf(seluf_(acc[r] + o3b));
            }
            __syncthreads();
            acc = mfma_layer<WBF>(T1B, wsO4, oW4, lm, kb, jo);
            if (act) {
#pragma unroll
                for (int r = 0; r < 4; ++r) {
                    const int ki = r * 256 + jo;
                    const float kc = acc[r] + o4b;
                    kstb[stage][ki] = f2bf(kc);
                    const float yv = h0[r][jo];
                    float sm;
                    switch (stage) {
                    case 0:
                        sm = A21 * kc;
                        break;
                    case 1: {
                        float k1v = bf2f(kstb[0][ki]);
                        sm = fmaf(A32, kc, A31 * k1v);
                        break; }
                    case 2: {
                        float k1v = bf2f(kstb[0][ki]), k2v = bf2f(kstb[1][ki]);
                        sm = fmaf(A43, kc, fmaf(A42, k2v, A41 * k1v));
                        break; }
                    case 3: {
                        float k1v = bf2f(kstb[0][ki]), k2v = bf2f(kstb[1][ki]);
                        float k3v = bf2f(kstb[2][ki]);
                        sm = fmaf(A54, kc, fmaf(A53, k3v, fmaf(A52, k2v, A51 * k1v)));
                        break; }
                    case 4: {
                        float k1v = bf2f(kstb[0][ki]), k2v = bf2f(kstb[1][ki]);
                        float k3v = bf2f(kstb[2][ki]), k4v = bf2f(kstb[3][ki]);
                        sm = fmaf(A65, kc, fmaf(A64, k4v,
                             fmaf(A63, k3v, fmaf(A62, k2v, A61 * k1v))));
                        break; }
                    default: {
                        float k1v = bf2f(kstb[0][ki]), k3v = bf2f(kstb[2][ki]);
                        float k4v = bf2f(kstb[3][ki]), k5v = bf2f(kstb[4][ki]);
                        sm = fmaf(B6f, kc, fmaf(B5f, k5v,
                             fmaf(B4f, k4v, fmaf(B3f, k3v, B1f * k1v))));
                        break; }
                    }
                    const float yn = fmaf(dtv[r], sm, yv);
                    if (stage < 5) {
                        YTB[midx(r, jo)] = f2bf(yn);
                    } else {
                        h0[r][jo] = yn;
                        YBF[midx(r, jo)] = f2bf(yn);
                    }
                }
            }
            __syncthreads();
        }
    }

    // ---- output head: 4 rows, one pass ----
    {
        const int R = tid >> 8;              // 0..3
        red[tid] = h0[R][t8] * outW[t8];
        __syncthreads();
        for (int sw = 128; sw > 0; sw >>= 1) {
            if (t8 < sw) red[tid] += red[tid + sw];
            __syncthreads();
        }
        if (t8 == 0) {
            float acc = red[tid] + outb[0];
#pragma unroll
            for (int mm = 0; mm < 4; ++mm) acc = fmaf(meta_s[R][mm], outW[HD + mm], acc);
            out[b0 + R] = acc;
        }
    }
}

extern "C" void kernel_launch(void* const* d_in, const int* in_sizes, int n_in,
                              void* d_out, int out_size, void* d_ws, size_t ws_size,
                              hipStream_t stream) {
    const float* x    = (const float*)d_in[0];
    const float* meta = (const float*)d_in[1];
    const float* W_ih = (const float*)d_in[2];
    const float* W_hh = (const float*)d_in[3];
    const float* b_ih = (const float*)d_in[4];
    const float* b_hh = (const float*)d_in[5];
    const float* eW1  = (const float*)d_in[6];
    const float* eb1  = (const float*)d_in[7];
    const float* eW2  = (const float*)d_in[8];
    const float* eb2  = (const float*)d_in[9];
    const float* oW1  = (const float*)d_in[10];
    const float* ob1  = (const float*)d_in[11];
    const float* oW2  = (const float*)d_in[12];
    const float* ob2  = (const float*)d_in[13];
    const float* oW3  = (const float*)d_in[14];
    const float* ob3  = (const float*)d_in[15];
    const float* oW4  = (const float*)d_in[16];
    const float* ob4  = (const float*)d_in[17];
    const float* outW = (const float*)d_in[18];
    const float* outb = (const float*)d_in[19];

    const size_t need = (size_t)655360 * sizeof(ushort_t);   // 1.31 MB
    const bool wbf = (d_ws != nullptr) && (ws_size >= need);

    if (wbf) {
        cvt_k<<<2560, 256, 0, stream>>>(oW1, oW2, oW3, oW4, W_hh, eW1, eW2,
                                        (ushort_t*)d_ws);
        fused_kernel<1><<<BSZ / RB, TB, 0, stream>>>(x, meta, W_ih, W_hh, b_ih, b_hh,
                                                     eW1, eb1, eW2, eb2,
                                                     oW1, ob1, oW2, ob2, oW3, ob3, oW4, ob4,
                                                     outW, outb, (const ushort_t*)d_ws,
                                                     (float*)d_out);
    } else {
        fused_kernel<0><<<BSZ / RB, TB, 0, stream>>>(x, meta, W_ih, W_hh, b_ih, b_hh,
                                                     eW1, eb1, eW2, eb2,
                                                     oW1, ob1, oW2, ob2, oW3, ob3, oW4, ob4,
                                                     outW, outb, (const ushort_t*)nullptr,
                                                     (float*)d_out);
    }
}

// Round 19
// 2614.102 us; speedup vs baseline: 2.8507x; 2.8507x over previous
//
#include <hip/hip_runtime.h>
#include <math.h>

#define HD   256
#define RB   8      // batch rows per block -> grid 256 = 1 block/CU (min weight traffic)
#define TB   1024   // 16 waves
#define TT   64
#define NST  32
#define BSZ  2048

typedef __attribute__((ext_vector_type(8))) short short8;
typedef __attribute__((ext_vector_type(4))) float f32x4;
typedef unsigned short ushort_t;

// ---------------- math helpers ----------------
__device__ __forceinline__ float sigmoidf_(float x) {
    return 1.0f / (1.0f + __expf(-x));
}
__device__ __forceinline__ float tanhf_(float x) {
    float e = __expf(2.0f * x);
    return 1.0f - 2.0f / (e + 1.0f);
}
__device__ __forceinline__ float seluf_(float x) {
    const float a = 1.6732632423543772f, s = 1.0507009873554805f;
    return x > 0.0f ? s * x : s * a * (__expf(x) - 1.0f);
}
__device__ __forceinline__ float erfinvf_(float x) {
    float w = -log1pf(-x * x);
    float p;
    if (w < 5.0f) {
        w -= 2.5f;
        p = 2.81022636e-08f;
        p = fmaf(p, w, 3.43273939e-07f);
        p = fmaf(p, w, -3.5233877e-06f);
        p = fmaf(p, w, -4.39150654e-06f);
        p = fmaf(p, w, 0.00021858087f);
        p = fmaf(p, w, -0.00125372503f);
        p = fmaf(p, w, -0.00417768164f);
        p = fmaf(p, w, 0.246640727f);
        p = fmaf(p, w, 1.50140941f);
    } else {
        w = sqrtf(w) - 3.0f;
        p = -0.000200214257f;
        p = fmaf(p, w, 0.000100950558f);
        p = fmaf(p, w, 0.00134934322f);
        p = fmaf(p, w, -0.00367342844f);
        p = fmaf(p, w, 0.00573950773f);
        p = fmaf(p, w, -0.0076224613f);
        p = fmaf(p, w, 0.00943887047f);
        p = fmaf(p, w, 1.00167406f);
        p = fmaf(p, w, 2.83297682f);
    }
    return p * x;
}

#define TF_ROUND(x0, x1, R) { x0 += x1; x1 = (x1 << (R)) | (x1 >> (32 - (R))); x1 ^= x0; }

__device__ __forceinline__ void threefry_(unsigned c0, unsigned c1, unsigned& r0, unsigned& r1) {
    const unsigned ks0 = 0u, ks1 = 42u, ks2 = 0x1BD11BDAu ^ 0u ^ 42u;
    unsigned x0 = c0 + ks0, x1 = c1 + ks1;
    TF_ROUND(x0,x1,13) TF_ROUND(x0,x1,15) TF_ROUND(x0,x1,26) TF_ROUND(x0,x1,6)
    x0 += ks1; x1 += ks2 + 1u;
    TF_ROUND(x0,x1,17) TF_ROUND(x0,x1,29) TF_ROUND(x0,x1,16) TF_ROUND(x0,x1,24)
    x0 += ks2; x1 += ks0 + 2u;
    TF_ROUND(x0,x1,13) TF_ROUND(x0,x1,15) TF_ROUND(x0,x1,26) TF_ROUND(x0,x1,6)
    x0 += ks0; x1 += ks1 + 3u;
    TF_ROUND(x0,x1,17) TF_ROUND(x0,x1,29) TF_ROUND(x0,x1,16) TF_ROUND(x0,x1,24)
    x0 += ks1; x1 += ks2 + 4u;
    TF_ROUND(x0,x1,13) TF_ROUND(x0,x1,15) TF_ROUND(x0,x1,26) TF_ROUND(x0,x1,6)
    x0 += ks2; x1 += ks0 + 5u;
    r0 = x0; r1 = x1;
}

// eps[i]: bits = o0 ^ o1 of threefry2x32(key(0,42), (0, i))  [verified round 5]
__device__ __forceinline__ float jax_normal_(unsigned i) {
    unsigned o0, o1;
    threefry_(0u, i, o0, o1);
    unsigned bits = o0 ^ o1;
    unsigned fb = (bits >> 9) | 0x3F800000u;
    float f = __uint_as_float(fb) - 1.0f;
    const float lo = -0.99999994f;
    float u = f * 2.0f + lo;
    u = fmaxf(lo, u);
    return 1.41421356237f * erfinvf_(u);
}

// fp32 <-> bf16
__device__ __forceinline__ ushort_t f2bf(float f) {
    unsigned u = __float_as_uint(f);
    return (ushort_t)((u + 0x7FFFu + ((u >> 16) & 1u)) >> 16);
}
__device__ __forceinline__ float bf2f(ushort_t u) {
    return __uint_as_float(((unsigned)u) << 16);
}

// swizzled bf16 mirror index (ushort units): row stride 256, 16B-chunk XOR swizzle
__device__ __forceinline__ int midx(int row, int k) {
    int chunk = k >> 3;
    return row * 256 + (((chunk ^ (row & 7)) << 3) | (k & 7));
}

// bf16 weight fragment load (WBF=1: from bf16 blob; else convert fp32 inline)
template<int WBF>
__device__ __forceinline__ short8 ldw(const ushort_t* __restrict__ Wbf,
                                      const float* __restrict__ Wf,
                                      int row, int k0) {
    if (WBF) {
        return *(const short8*)(Wbf + (size_t)row * 256 + k0);
    } else {
        const float4 w0 = *(const float4*)(Wf + (size_t)row * 256 + k0);
        const float4 w1 = *(const float4*)(Wf + (size_t)row * 256 + k0 + 4);
        union { ushort_t u[8]; short8 v; } bb;
        bb.u[0] = f2bf(w0.x); bb.u[1] = f2bf(w0.y); bb.u[2] = f2bf(w0.z); bb.u[3] = f2bf(w0.w);
        bb.u[4] = f2bf(w1.x); bb.u[5] = f2bf(w1.y); bb.u[6] = f2bf(w1.z); bb.u[7] = f2bf(w1.w);
        return bb.v;
    }
}

// MFMA 256->256 layer slice: inline B loads (no persistent buffer -> no spill)
template<int WBF>
__device__ __forceinline__ f32x4 mfma_layer(const ushort_t* __restrict__ inbf,
                                            const ushort_t* __restrict__ Wbf,
                                            const float* __restrict__ Wf,
                                            const int lm, const int kb, const int jo)
{
    f32x4 acc = {0.f, 0.f, 0.f, 0.f};
#pragma unroll
    for (int kt = 0; kt < 8; ++kt) {
        const int k0 = kt * 32 + kb * 8;
        short8 a = *(const short8*)(inbf + midx(lm, k0));
        short8 b = ldw<WBF>(Wbf, Wf, jo, k0);
        acc = __builtin_amdgcn_mfma_f32_16x16x32_bf16(a, b, acc, 0, 0, 0);
    }
    return acc;
}

// ---------------- weight bf16 conversion prepass ----------------
// elements: [0,256K) O1..O4 | [256K,448K) Whh | [448K,512K) E1 | [512K,640K) E2
__global__ void cvt_k(const float* __restrict__ o1, const float* __restrict__ o2,
                      const float* __restrict__ o3, const float* __restrict__ o4,
                      const float* __restrict__ whh, const float* __restrict__ e1,
                      const float* __restrict__ e2, ushort_t* __restrict__ out) {
    int i = blockIdx.x * blockDim.x + threadIdx.x;
    if (i < 262144) {
        int m = i >> 16, r = i & 65535;
        const float* s = (m == 0) ? o1 : (m == 1) ? o2 : (m == 2) ? o3 : o4;
        out[i] = f2bf(s[r]);
    } else if (i < 458752) {
        out[i] = f2bf(whh[i - 262144]);
    } else if (i < 524288) {
        out[i] = f2bf(e1[i - 458752]);
    } else if (i < 655360) {
        out[i] = f2bf(e2[i - 524288]);
    }
}

// ---------------- fused pipeline kernel ----------------
// Config: RB=8/grid=256 (min weight traffic), launch_bounds(TB,4) = 128 unified regs
// (64 arch + 64 acc). Inline B loads keep arch demand ~45 -> NO spill (R18 body).
// LDS ~76 KB (R17 diet: MFMA encoder, bf16 k-store).
template<int WBF>
__global__ __launch_bounds__(TB, 4) void fused_kernel(
    const float* __restrict__ x,
    const float* __restrict__ meta,
    const float* __restrict__ W_ih,
    const float* __restrict__ W_hh,
    const float* __restrict__ b_ih,
    const float* __restrict__ b_hh,
    const float* __restrict__ eW1,
    const float* __restrict__ eb1,
    const float* __restrict__ eW2,
    const float* __restrict__ eb2,
    const float* __restrict__ oW1, const float* __restrict__ ob1,
    const float* __restrict__ oW2, const float* __restrict__ ob2,
    const float* __restrict__ oW3, const float* __restrict__ ob3,
    const float* __restrict__ oW4, const float* __restrict__ ob4,
    const float* __restrict__ outW,
    const float* __restrict__ outb,
    const ushort_t* __restrict__ wsbf,
    float* __restrict__ out)
{
    const int tid = threadIdx.x;
    const int t8  = tid & 255;
    // MFMA mapping
    const int l   = tid & 63;
    const int w   = tid >> 6;            // wave / n-tile base
    const int lm  = l & 15;              // A batch-row / B out-col within tile
    const int kb  = l >> 4;              // k-slice
    const int jo  = w * 16 + lm;         // owned output col (0..255)
    const int er2 = (l >> 4) & 1;        // epilogue row group
    const bool act = (l < 32);           // lanes 0..31 cover rows 0..7
    const int b0  = blockIdx.x * RB;

    __shared__ float h0[RB][HD];                        // 8 KB fp32 h / y master
    __shared__ float xall[RB][TT * 4];                  // 8 KB
    __shared__ float red[TB];                           // 4 KB
    __shared__ __align__(16) ushort_t mir[4][16][256];  // 32 KB bf16 mirrors
    __shared__ ushort_t kstb[6][RB * 256];              // 24 KB bf16 k-store
    __shared__ float meta_s[RB][4];
    __shared__ float dt_s[RB];
    // total ~76.3 KB

    ushort_t* YBF = &mir[0][0][0];
    ushort_t* YTB = &mir[1][0][0];
    ushort_t* T1B = &mir[2][0][0];
    ushort_t* T2B = &mir[3][0][0];
    const ushort_t* wsO1  = wsbf;
    const ushort_t* wsO2  = wsbf + 65536;
    const ushort_t* wsO3  = wsbf + 131072;
    const ushort_t* wsO4  = wsbf + 196608;
    const ushort_t* wsWhh = wsbf + 262144;
    const ushort_t* wsE1  = wsbf + 458752;
    const ushort_t* wsE2  = wsbf + 524288;

    // ---- stage x, meta; zero h0 and mirrors ----
#pragma unroll
    for (int i = 0; i < 2; ++i) {
        int idx = tid + i * TB;
        int r = idx >> 8, c = idx & 255;
        xall[r][c] = x[(size_t)(b0 + r) * 256 + c];
    }
    if (tid < RB * 4) { int r = tid >> 2, mm = tid & 3; meta_s[r][mm] = meta[(b0 + r) * 4 + mm]; }
    if (tid < 2 * HD) { int r = tid >> 8, c = tid & 255;
        h0[r][c] = 0.0f; h0[r + 2][c] = 0.0f; h0[r + 4][c] = 0.0f; h0[r + 6][c] = 0.0f; }
    {
        unsigned* mz = (unsigned*)&mir[0][0][0];   // 8192 u32 = 32 KB
#pragma unroll
        for (int i = 0; i < 8; ++i) mz[tid + i * TB] = 0u;
    }
    __syncthreads();
    if (tid < RB) dt_s[tid] = (xall[tid][TT * 4 - 4] - xall[tid][0]) * (1.0f / (float)NST);

    // ---- GRU per-lane x-side constants for owned col jo ----
    float wxr[4], wxz[4], wxn[4];
#pragma unroll
    for (int d = 0; d < 4; ++d) {
        wxr[d] = W_ih[(size_t)jo * 8 + d];
        wxz[d] = W_ih[(size_t)(jo + 256) * 8 + d];
        wxn[d] = W_ih[(size_t)(jo + 512) * 8 + d];
    }
    float base_r[4], base_z[4], base_xn[4];
    {
        float mwr[4], mwz[4], mwn[4];
#pragma unroll
        for (int mm = 0; mm < 4; ++mm) {
            mwr[mm] = W_ih[(size_t)jo * 8 + 4 + mm];
            mwz[mm] = W_ih[(size_t)(jo + 256) * 8 + 4 + mm];
            mwn[mm] = W_ih[(size_t)(jo + 512) * 8 + 4 + mm];
        }
        const float bir = b_ih[jo], biz = b_ih[jo + 256], bin_ = b_ih[jo + 512];
        const float bhr = b_hh[jo], bhz = b_hh[jo + 256];
#pragma unroll
        for (int r = 0; r < 4; ++r) {
            const int R = er2 * 4 + r;
            float sr = bir + bhr, sz = biz + bhz, sn = bin_;
#pragma unroll
            for (int mm = 0; mm < 4; ++mm) {
                float mv = meta_s[R][mm];
                sr = fmaf(mv, mwr[mm], sr);
                sz = fmaf(mv, mwz[mm], sz);
                sn = fmaf(mv, mwn[mm], sn);
            }
            base_r[r] = sr; base_z[r] = sz; base_xn[r] = sn;
        }
    }
    const float bhn = b_hh[512 + jo];

    // ---- GRU: 64 steps, MFMA bf16 (inline B), mirror ping-pong, ONE barrier/step ----
    int p = 0;
#pragma unroll 1
    for (int t = 0; t < TT; ++t) {
        const ushort_t* YHp = &mir[p][0][0];
        f32x4 aR = {0.f,0.f,0.f,0.f}, aZ = {0.f,0.f,0.f,0.f}, aN = {0.f,0.f,0.f,0.f};
#pragma unroll 2
        for (int kt = 0; kt < 8; ++kt) {
            const int k0 = kt * 32 + kb * 8;
            short8 a = *(const short8*)(YHp + midx(lm, k0));
            short8 b = ldw<WBF>(wsWhh, W_hh, jo, k0);
            aR = __builtin_amdgcn_mfma_f32_16x16x32_bf16(a, b, aR, 0, 0, 0);
            b = ldw<WBF>(wsWhh, W_hh, jo + 256, k0);
            aZ = __builtin_amdgcn_mfma_f32_16x16x32_bf16(a, b, aZ, 0, 0, 0);
            b = ldw<WBF>(wsWhh, W_hh, jo + 512, k0);
            aN = __builtin_amdgcn_mfma_f32_16x16x32_bf16(a, b, aN, 0, 0, 0);
        }
        if (act) {
            ushort_t* YHn = &mir[p ^ 1][0][0];
#pragma unroll
            for (int r = 0; r < 4; ++r) {
                const int R = er2 * 4 + r;
                float xr = base_r[r], xz = base_z[r], xn = base_xn[r];
#pragma unroll
                for (int d = 0; d < 4; ++d) {
                    float xv = xall[R][t * 4 + d];
                    xr = fmaf(xv, wxr[d], xr);
                    xz = fmaf(xv, wxz[d], xz);
                    xn = fmaf(xv, wxn[d], xn);
                }
                float rg = sigmoidf_(xr + aR[r]);
                float zg = sigmoidf_(xz + aZ[r]);
                float ng = tanhf_(fmaf(rg, aN[r] + bhn, xn));
                float hp = h0[R][jo];
                float hnew = fmaf(zg, hp - ng, ng);
                h0[R][jo] = hnew;
                YHn[midx(R, jo)] = f2bf(hnew);
            }
        }
        __syncthreads();
        p ^= 1;
    }
    // final h bf16 in mir[0] (= YBF), fp32 in h0

    // ---- encoder (MFMA bf16): h1 = relu(h@E1+b1); mean/std; sample y0 ----
    {
        f32x4 acc = mfma_layer<WBF>(YBF, wsE1, eW1, lm, kb, jo);
        if (act) {
            const float eb1j = eb1[jo];
#pragma unroll
            for (int r = 0; r < 4; ++r)
                T1B[midx(er2 * 4 + r, jo)] = f2bf(fmaxf(acc[r] + eb1j, 0.0f));
        }
        __syncthreads();

        f32x4 aM = mfma_layer<WBF>(T1B, wsE2, eW2, lm, kb, jo);
        f32x4 aS = mfma_layer<WBF>(T1B, wsE2 + 65536, eW2 + 65536, lm, kb, jo);
        if (act) {
            const float bm = eb2[jo], bs = eb2[256 + jo];
#pragma unroll
            for (int r = 0; r < 4; ++r) {
                const int row = er2 * 4 + r;
                float e = jax_normal_((unsigned)((b0 + row) * HD + jo));
                float y0v = fmaf(e, aS[r] + bs, aM[r] + bm);
                h0[row][jo] = y0v;
                YBF[midx(row, jo)] = f2bf(y0v);
            }
        }
        __syncthreads();
    }

    // ---- dopri5: MFMA bf16 ODE (inline B); k's in bf16 LDS ----
    const float A21 = (float)(1.0/5.0);
    const float A31 = (float)(3.0/40.0),      A32 = (float)(9.0/40.0);
    const float A41 = (float)(44.0/45.0),     A42 = (float)(-56.0/15.0),    A43 = (float)(32.0/9.0);
    const float A51 = (float)(19372.0/6561.0),A52 = (float)(-25360.0/2187.0),
                A53 = (float)(64448.0/6561.0),A54 = (float)(-212.0/729.0);
    const float A61 = (float)(9017.0/3168.0), A62 = (float)(-355.0/33.0),
                A63 = (float)(46732.0/5247.0),A64 = (float)(49.0/176.0),    A65 = (float)(-5103.0/18656.0);
    const float B1f = (float)(35.0/384.0),    B3f = (float)(500.0/1113.0),  B4f = (float)(125.0/192.0),
                B5f = (float)(-2187.0/6784.0),B6f = (float)(11.0/84.0);

    const float o1b = ob1[jo], o2b = ob2[jo], o3b = ob3[jo], o4b = ob4[jo];
    float dtv[4];
    if (act) {
#pragma unroll
        for (int r = 0; r < 4; ++r) dtv[r] = dt_s[er2 * 4 + r];
    }

#pragma unroll 1
    for (int st = 0; st < NST; ++st) {
#pragma unroll 1
        for (int stage = 0; stage < 6; ++stage) {
            const ushort_t* in0 = (stage == 0) ? YBF : YTB;
            f32x4 acc = mfma_layer<WBF>(in0, wsO1, oW1, lm, kb, jo);
            if (act) {
#pragma unroll
                for (int r = 0; r < 4; ++r)
                    T1B[midx(er2 * 4 + r, jo)] = f2bf(seluf_(acc[r] + o1b));
            }
            __syncthreads();
            acc = mfma_layer<WBF>(T1B, wsO2, oW2, lm, kb, jo);
            if (act) {
#pragma unroll
                for (int r = 0; r < 4; ++r)
                    T2B[midx(er2 * 4 + r, jo)] = f2bf(seluf_(acc[r] + o2b));
            }
            __syncthreads();
            acc = mfma_layer<WBF>(T2B, wsO3, oW3, lm, kb, jo);
            if (act) {
#pragma unroll
                for (int r = 0; r < 4; ++r)
                    T1B[midx(er2 * 4 + r, jo)] = f2bf(seluf_(acc[r] + o3b));
            }
            __syncthreads();
            acc = mfma_layer<WBF>(T1B, wsO4, oW4, lm, kb, jo);
            if (act) {
#pragma unroll
                for (int r = 0; r < 4; ++r) {
                    const int row = er2 * 4 + r;
                    const int ki = row * 256 + jo;
                    const float kc = acc[r] + o4b;
                    kstb[stage][ki] = f2bf(kc);
                    const float yv = h0[row][jo];
                    float sm;
                    switch (stage) {
                    case 0:
                        sm = A21 * kc;
                        break;
                    case 1: {
                        float k1v = bf2f(kstb[0][ki]);
                        sm = fmaf(A32, kc, A31 * k1v);
                        break; }
                    case 2: {
                        float k1v = bf2f(kstb[0][ki]), k2v = bf2f(kstb[1][ki]);
                        sm = fmaf(A43, kc, fmaf(A42, k2v, A41 * k1v));
                        break; }
                    case 3: {
                        float k1v = bf2f(kstb[0][ki]), k2v = bf2f(kstb[1][ki]);
                        float k3v = bf2f(kstb[2][ki]);
                        sm = fmaf(A54, kc, fmaf(A53, k3v, fmaf(A52, k2v, A51 * k1v)));
                        break; }
                    case 4: {
                        float k1v = bf2f(kstb[0][ki]), k2v = bf2f(kstb[1][ki]);
                        float k3v = bf2f(kstb[2][ki]), k4v = bf2f(kstb[3][ki]);
                        sm = fmaf(A65, kc, fmaf(A64, k4v,
                             fmaf(A63, k3v, fmaf(A62, k2v, A61 * k1v))));
                        break; }
                    default: {
                        float k1v = bf2f(kstb[0][ki]), k3v = bf2f(kstb[2][ki]);
                        float k4v = bf2f(kstb[3][ki]), k5v = bf2f(kstb[4][ki]);
                        sm = fmaf(B6f, kc, fmaf(B5f, k5v,
                             fmaf(B4f, k4v, fmaf(B3f, k3v, B1f * k1v))));
                        break; }
                    }
                    const float yn = fmaf(dtv[r], sm, yv);
                    if (stage < 5) {
                        YTB[midx(row, jo)] = f2bf(yn);
                    } else {
                        h0[row][jo] = yn;
                        YBF[midx(row, jo)] = f2bf(yn);
                    }
                }
            }
            __syncthreads();
        }
    }

    // ---- output head: 4 rows per pass ----
#pragma unroll 1
    for (int rp4 = 0; rp4 < 2; ++rp4) {
        const int R = rp4 * 4 + (tid >> 8);
        red[tid] = h0[R][t8] * outW[t8];
        __syncthreads();
        for (int sw = 128; sw > 0; sw >>= 1) {
            if (t8 < sw) red[tid] += red[tid + sw];
            __syncthreads();
        }
        if (t8 == 0) {
            float acc = red[tid] + outb[0];
#pragma unroll
            for (int mm = 0; mm < 4; ++mm) acc = fmaf(meta_s[R][mm], outW[HD + mm], acc);
            out[b0 + R] = acc;
        }
        __syncthreads();
    }
}

extern "C" void kernel_launch(void* const* d_in, const int* in_sizes, int n_in,
                              void* d_out, int out_size, void* d_ws, size_t ws_size,
                              hipStream_t stream) {
    const float* x    = (const float*)d_in[0];
    const float* meta = (const float*)d_in[1];
    const float* W_ih = (const float*)d_in[2];
    const float* W_hh = (const float*)d_in[3];
    const float* b_ih = (const float*)d_in[4];
    const float* b_hh = (const float*)d_in[5];
    const float* eW1  = (const float*)d_in[6];
    const float* eb1  = (const float*)d_in[7];
    const float* eW2  = (const float*)d_in[8];
    const float* eb2  = (const float*)d_in[9];
    const float* oW1  = (const float*)d_in[10];
    const float* ob1  = (const float*)d_in[11];
    const float* oW2  = (const float*)d_in[12];
    const float* ob2  = (const float*)d_in[13];
    const float* oW3  = (const float*)d_in[14];
    const float* ob3  = (const float*)d_in[15];
    const float* oW4  = (const float*)d_in[16];
    const float* ob4  = (const float*)d_in[17];
    const float* outW = (const float*)d_in[18];
    const float* outb = (const float*)d_in[19];

    const size_t need = (size_t)655360 * sizeof(ushort_t);   // 1.31 MB
    const bool wbf = (d_ws != nullptr) && (ws_size >= need);

    if (wbf) {
        cvt_k<<<2560, 256, 0, stream>>>(oW1, oW2, oW3, oW4, W_hh, eW1, eW2,
                                        (ushort_t*)d_ws);
        fused_kernel<1><<<BSZ / RB, TB, 0, stream>>>(x, meta, W_ih, W_hh, b_ih, b_hh,
                                                     eW1, eb1, eW2, eb2,
                                                     oW1, ob1, oW2, ob2, oW3, ob3, oW4, ob4,
                                                     outW, outb, (const ushort_t*)d_ws,
                                                     (float*)d_out);
    } else {
        fused_kernel<0><<<BSZ / RB, TB, 0, stream>>>(x, meta, W_ih, W_hh, b_ih, b_hh,
                                                     eW1, eb1, eW2, eb2,
                                                     oW1, ob1, oW2, ob2, oW3, ob3, oW4, ob4,
                                                     outW, outb, (const ushort_t*)nullptr,
                                                     (float*)d_out);
    }
}

// Round 20
// 2208.203 us; speedup vs baseline: 3.3747x; 1.1838x over previous
//
#include <hip/hip_runtime.h>
#include <math.h>

#define HD   256
#define RB   16     // batch rows per block == MFMA tile M (no padding) -> grid 128
#define TB   1024   // 16 waves
#define TT   64
#define NST  32
#define BSZ  2048

typedef __attribute__((ext_vector_type(8))) short short8;
typedef __attribute__((ext_vector_type(4))) float f32x4;
typedef unsigned short ushort_t;

// ---------------- math helpers ----------------
__device__ __forceinline__ float sigmoidf_(float x) {
    return 1.0f / (1.0f + __expf(-x));
}
__device__ __forceinline__ float tanhf_(float x) {
    float e = __expf(2.0f * x);
    return 1.0f - 2.0f / (e + 1.0f);
}
__device__ __forceinline__ float seluf_(float x) {
    const float a = 1.6732632423543772f, s = 1.0507009873554805f;
    return x > 0.0f ? s * x : s * a * (__expf(x) - 1.0f);
}
__device__ __forceinline__ float erfinvf_(float x) {
    float w = -log1pf(-x * x);
    float p;
    if (w < 5.0f) {
        w -= 2.5f;
        p = 2.81022636e-08f;
        p = fmaf(p, w, 3.43273939e-07f);
        p = fmaf(p, w, -3.5233877e-06f);
        p = fmaf(p, w, -4.39150654e-06f);
        p = fmaf(p, w, 0.00021858087f);
        p = fmaf(p, w, -0.00125372503f);
        p = fmaf(p, w, -0.00417768164f);
        p = fmaf(p, w, 0.246640727f);
        p = fmaf(p, w, 1.50140941f);
    } else {
        w = sqrtf(w) - 3.0f;
        p = -0.000200214257f;
        p = fmaf(p, w, 0.000100950558f);
        p = fmaf(p, w, 0.00134934322f);
        p = fmaf(p, w, -0.00367342844f);
        p = fmaf(p, w, 0.00573950773f);
        p = fmaf(p, w, -0.0076224613f);
        p = fmaf(p, w, 0.00943887047f);
        p = fmaf(p, w, 1.00167406f);
        p = fmaf(p, w, 2.83297682f);
    }
    return p * x;
}

#define TF_ROUND(x0, x1, R) { x0 += x1; x1 = (x1 << (R)) | (x1 >> (32 - (R))); x1 ^= x0; }

__device__ __forceinline__ void threefry_(unsigned c0, unsigned c1, unsigned& r0, unsigned& r1) {
    const unsigned ks0 = 0u, ks1 = 42u, ks2 = 0x1BD11BDAu ^ 0u ^ 42u;
    unsigned x0 = c0 + ks0, x1 = c1 + ks1;
    TF_ROUND(x0,x1,13) TF_ROUND(x0,x1,15) TF_ROUND(x0,x1,26) TF_ROUND(x0,x1,6)
    x0 += ks1; x1 += ks2 + 1u;
    TF_ROUND(x0,x1,17) TF_ROUND(x0,x1,29) TF_ROUND(x0,x1,16) TF_ROUND(x0,x1,24)
    x0 += ks2; x1 += ks0 + 2u;
    TF_ROUND(x0,x1,13) TF_ROUND(x0,x1,15) TF_ROUND(x0,x1,26) TF_ROUND(x0,x1,6)
    x0 += ks0; x1 += ks1 + 3u;
    TF_ROUND(x0,x1,17) TF_ROUND(x0,x1,29) TF_ROUND(x0,x1,16) TF_ROUND(x0,x1,24)
    x0 += ks1; x1 += ks2 + 4u;
    TF_ROUND(x0,x1,13) TF_ROUND(x0,x1,15) TF_ROUND(x0,x1,26) TF_ROUND(x0,x1,6)
    x0 += ks2; x1 += ks0 + 5u;
    r0 = x0; r1 = x1;
}

// eps[i]: bits = o0 ^ o1 of threefry2x32(key(0,42), (0, i))  [verified round 5]
__device__ __forceinline__ float jax_normal_(unsigned i) {
    unsigned o0, o1;
    threefry_(0u, i, o0, o1);
    unsigned bits = o0 ^ o1;
    unsigned fb = (bits >> 9) | 0x3F800000u;
    float f = __uint_as_float(fb) - 1.0f;
    const float lo = -0.99999994f;
    float u = f * 2.0f + lo;
    u = fmaxf(lo, u);
    return 1.41421356237f * erfinvf_(u);
}

// fp32 <-> bf16
__device__ __forceinline__ ushort_t f2bf(float f) {
    unsigned u = __float_as_uint(f);
    return (ushort_t)((u + 0x7FFFu + ((u >> 16) & 1u)) >> 16);
}
__device__ __forceinline__ float bf2f(ushort_t u) {
    return __uint_as_float(((unsigned)u) << 16);
}

// swizzled bf16 mirror index (ushort units): row stride 256, 16B-chunk XOR swizzle
__device__ __forceinline__ int midx(int row, int k) {
    int chunk = k >> 3;
    return row * 256 + (((chunk ^ (row & 7)) << 3) | (k & 7));
}

// bf16 weight fragment load (WBF=1: from bf16 blob; else convert fp32 inline)
template<int WBF>
__device__ __forceinline__ short8 ldw(const ushort_t* __restrict__ Wbf,
                                      const float* __restrict__ Wf,
                                      int row, int k0) {
    if (WBF) {
        return *(const short8*)(Wbf + (size_t)row * 256 + k0);
    } else {
        const float4 w0 = *(const float4*)(Wf + (size_t)row * 256 + k0);
        const float4 w1 = *(const float4*)(Wf + (size_t)row * 256 + k0 + 4);
        union { ushort_t u[8]; short8 v; } bb;
        bb.u[0] = f2bf(w0.x); bb.u[1] = f2bf(w0.y); bb.u[2] = f2bf(w0.z); bb.u[3] = f2bf(w0.w);
        bb.u[4] = f2bf(w1.x); bb.u[5] = f2bf(w1.y); bb.u[6] = f2bf(w1.z); bb.u[7] = f2bf(w1.w);
        return bb.v;
    }
}

// MFMA 256->256 layer slice: inline B loads (no persistent buffer -> no spill)
template<int WBF>
__device__ __forceinline__ f32x4 mfma_layer(const ushort_t* __restrict__ inbf,
                                            const ushort_t* __restrict__ Wbf,
                                            const float* __restrict__ Wf,
                                            const int lm, const int kb, const int jo)
{
    f32x4 acc = {0.f, 0.f, 0.f, 0.f};
#pragma unroll
    for (int kt = 0; kt < 8; ++kt) {
        const int k0 = kt * 32 + kb * 8;
        short8 a = *(const short8*)(inbf + midx(lm, k0));
        short8 b = ldw<WBF>(Wbf, Wf, jo, k0);
        acc = __builtin_amdgcn_mfma_f32_16x16x32_bf16(a, b, acc, 0, 0, 0);
    }
    return acc;
}

// ---------------- weight bf16 conversion prepass ----------------
// elements: [0,256K) O1..O4 | [256K,448K) Whh | [448K,512K) E1 | [512K,640K) E2
__global__ void cvt_k(const float* __restrict__ o1, const float* __restrict__ o2,
                      const float* __restrict__ o3, const float* __restrict__ o4,
                      const float* __restrict__ whh, const float* __restrict__ e1,
                      const float* __restrict__ e2, ushort_t* __restrict__ out) {
    int i = blockIdx.x * blockDim.x + threadIdx.x;
    if (i < 262144) {
        int m = i >> 16, r = i & 65535;
        const float* s = (m == 0) ? o1 : (m == 1) ? o2 : (m == 2) ? o3 : o4;
        out[i] = f2bf(s[r]);
    } else if (i < 458752) {
        out[i] = f2bf(whh[i - 262144]);
    } else if (i < 524288) {
        out[i] = f2bf(e1[i - 458752]);
    } else if (i < 655360) {
        out[i] = f2bf(e2[i - 524288]);
    }
}

// ---------------- fused pipeline kernel ----------------
// RB=16: full M=16 MFMA tiles (no padding) -> grid 128, total weight traffic halves.
// launch_bounds(TB,4) = 128 unified regs; inline B loads keep arch ~50 -> no spill.
// LDS ~116 KB -> 1 block/CU.
template<int WBF>
__global__ __launch_bounds__(TB, 4) void fused_kernel(
    const float* __restrict__ x,
    const float* __restrict__ meta,
    const float* __restrict__ W_ih,
    const float* __restrict__ W_hh,
    const float* __restrict__ b_ih,
    const float* __restrict__ b_hh,
    const float* __restrict__ eW1,
    const float* __restrict__ eb1,
    const float* __restrict__ eW2,
    const float* __restrict__ eb2,
    const float* __restrict__ oW1, const float* __restrict__ ob1,
    const float* __restrict__ oW2, const float* __restrict__ ob2,
    const float* __restrict__ oW3, const float* __restrict__ ob3,
    const float* __restrict__ oW4, const float* __restrict__ ob4,
    const float* __restrict__ outW,
    const float* __restrict__ outb,
    const ushort_t* __restrict__ wsbf,
    float* __restrict__ out)
{
    const int tid = threadIdx.x;
    const int t8  = tid & 255;
    // MFMA mapping
    const int l   = tid & 63;
    const int w   = tid >> 6;            // wave / n-tile base
    const int lm  = l & 15;              // A batch-row index source / B out-col within tile
    const int kb  = l >> 4;              // k-slice
    const int jo  = w * 16 + lm;         // owned output col (0..255)
    const int er4 = l >> 4;              // epilogue row group: rows er4*4 + r (ALL real)
    const int b0  = blockIdx.x * RB;

    __shared__ float h0[RB][HD];                        // 16 KB fp32 h / y master
    __shared__ float xall[RB][TT * 4];                  // 16 KB
    __shared__ float red[TB];                           // 4 KB
    __shared__ __align__(16) ushort_t mir[4][RB][256];  // 32 KB bf16 mirrors
    __shared__ ushort_t kstb[6][RB * 256];              // 48 KB bf16 k-store
    __shared__ float meta_s[RB][4];
    __shared__ float dt_s[RB];
    // total ~116.3 KB -> 1 block/CU

    ushort_t* YBF = &mir[0][0][0];
    ushort_t* YTB = &mir[1][0][0];
    ushort_t* T1B = &mir[2][0][0];
    ushort_t* T2B = &mir[3][0][0];
    const ushort_t* wsO1  = wsbf;
    const ushort_t* wsO2  = wsbf + 65536;
    const ushort_t* wsO3  = wsbf + 131072;
    const ushort_t* wsO4  = wsbf + 196608;
    const ushort_t* wsWhh = wsbf + 262144;
    const ushort_t* wsE1  = wsbf + 458752;
    const ushort_t* wsE2  = wsbf + 524288;

    // ---- stage x, meta; zero h0 and mirrors ----
#pragma unroll
    for (int i = 0; i < 4; ++i) {
        int idx = tid + i * TB;              // 0..4095
        int r = idx >> 8, c = idx & 255;
        xall[r][c] = x[(size_t)(b0 + r) * 256 + c];
        h0[r][c] = 0.0f;
    }
    if (tid < RB * 4) { int r = tid >> 2, mm = tid & 3; meta_s[r][mm] = meta[(b0 + r) * 4 + mm]; }
    {
        unsigned* mz = (unsigned*)&mir[0][0][0];   // 8192 u32 = 32 KB
#pragma unroll
        for (int i = 0; i < 8; ++i) mz[tid + i * TB] = 0u;
    }
    __syncthreads();
    if (tid < RB) dt_s[tid] = (xall[tid][TT * 4 - 4] - xall[tid][0]) * (1.0f / (float)NST);

    // ---- GRU per-lane x-side constants for owned col jo ----
    float wxr[4], wxz[4], wxn[4];
#pragma unroll
    for (int d = 0; d < 4; ++d) {
        wxr[d] = W_ih[(size_t)jo * 8 + d];
        wxz[d] = W_ih[(size_t)(jo + 256) * 8 + d];
        wxn[d] = W_ih[(size_t)(jo + 512) * 8 + d];
    }
    float base_r[4], base_z[4], base_xn[4];
    {
        float mwr[4], mwz[4], mwn[4];
#pragma unroll
        for (int mm = 0; mm < 4; ++mm) {
            mwr[mm] = W_ih[(size_t)jo * 8 + 4 + mm];
            mwz[mm] = W_ih[(size_t)(jo + 256) * 8 + 4 + mm];
            mwn[mm] = W_ih[(size_t)(jo + 512) * 8 + 4 + mm];
        }
        const float bir = b_ih[jo], biz = b_ih[jo + 256], bin_ = b_ih[jo + 512];
        const float bhr = b_hh[jo], bhz = b_hh[jo + 256];
#pragma unroll
        for (int r = 0; r < 4; ++r) {
            const int R = er4 * 4 + r;
            float sr = bir + bhr, sz = biz + bhz, sn = bin_;
#pragma unroll
            for (int mm = 0; mm < 4; ++mm) {
                float mv = meta_s[R][mm];
                sr = fmaf(mv, mwr[mm], sr);
                sz = fmaf(mv, mwz[mm], sz);
                sn = fmaf(mv, mwn[mm], sn);
            }
            base_r[r] = sr; base_z[r] = sz; base_xn[r] = sn;
        }
    }
    const float bhn = b_hh[512 + jo];

    // ---- GRU: 64 steps, MFMA bf16 (inline B), mirror ping-pong, ONE barrier/step ----
    int p = 0;
#pragma unroll 1
    for (int t = 0; t < TT; ++t) {
        const ushort_t* YHp = &mir[p][0][0];
        f32x4 aR = {0.f,0.f,0.f,0.f}, aZ = {0.f,0.f,0.f,0.f}, aN = {0.f,0.f,0.f,0.f};
#pragma unroll 2
        for (int kt = 0; kt < 8; ++kt) {
            const int k0 = kt * 32 + kb * 8;
            short8 a = *(const short8*)(YHp + midx(lm, k0));
            short8 b = ldw<WBF>(wsWhh, W_hh, jo, k0);
            aR = __builtin_amdgcn_mfma_f32_16x16x32_bf16(a, b, aR, 0, 0, 0);
            b = ldw<WBF>(wsWhh, W_hh, jo + 256, k0);
            aZ = __builtin_amdgcn_mfma_f32_16x16x32_bf16(a, b, aZ, 0, 0, 0);
            b = ldw<WBF>(wsWhh, W_hh, jo + 512, k0);
            aN = __builtin_amdgcn_mfma_f32_16x16x32_bf16(a, b, aN, 0, 0, 0);
        }
        {
            ushort_t* YHn = &mir[p ^ 1][0][0];
#pragma unroll
            for (int r = 0; r < 4; ++r) {
                const int R = er4 * 4 + r;
                float xr = base_r[r], xz = base_z[r], xn = base_xn[r];
#pragma unroll
                for (int d = 0; d < 4; ++d) {
                    float xv = xall[R][t * 4 + d];
                    xr = fmaf(xv, wxr[d], xr);
                    xz = fmaf(xv, wxz[d], xz);
                    xn = fmaf(xv, wxn[d], xn);
                }
                float rg = sigmoidf_(xr + aR[r]);
                float zg = sigmoidf_(xz + aZ[r]);
                float ng = tanhf_(fmaf(rg, aN[r] + bhn, xn));
                float hp = h0[R][jo];
                float hnew = fmaf(zg, hp - ng, ng);
                h0[R][jo] = hnew;
                YHn[midx(R, jo)] = f2bf(hnew);
            }
        }
        __syncthreads();
        p ^= 1;
    }
    // final h bf16 in mir[0] (= YBF), fp32 in h0

    // ---- encoder (MFMA bf16): h1 = relu(h@E1+b1); mean/std; sample y0 ----
    {
        f32x4 acc = mfma_layer<WBF>(YBF, wsE1, eW1, lm, kb, jo);
        {
            const float eb1j = eb1[jo];
#pragma unroll
            for (int r = 0; r < 4; ++r)
                T1B[midx(er4 * 4 + r, jo)] = f2bf(fmaxf(acc[r] + eb1j, 0.0f));
        }
        __syncthreads();

        f32x4 aM = mfma_layer<WBF>(T1B, wsE2, eW2, lm, kb, jo);
        f32x4 aS = mfma_layer<WBF>(T1B, wsE2 + 65536, eW2 + 65536, lm, kb, jo);
        {
            const float bm = eb2[jo], bs = eb2[256 + jo];
#pragma unroll
            for (int r = 0; r < 4; ++r) {
                const int row = er4 * 4 + r;
                float e = jax_normal_((unsigned)((b0 + row) * HD + jo));
                float y0v = fmaf(e, aS[r] + bs, aM[r] + bm);
                h0[row][jo] = y0v;
                YBF[midx(row, jo)] = f2bf(y0v);
            }
        }
        __syncthreads();
    }

    // ---- dopri5: MFMA bf16 ODE (inline B); k's in bf16 LDS ----
    const float A21 = (float)(1.0/5.0);
    const float A31 = (float)(3.0/40.0),      A32 = (float)(9.0/40.0);
    const float A41 = (float)(44.0/45.0),     A42 = (float)(-56.0/15.0),    A43 = (float)(32.0/9.0);
    const float A51 = (float)(19372.0/6561.0),A52 = (float)(-25360.0/2187.0),
                A53 = (float)(64448.0/6561.0),A54 = (float)(-212.0/729.0);
    const float A61 = (float)(9017.0/3168.0), A62 = (float)(-355.0/33.0),
                A63 = (float)(46732.0/5247.0),A64 = (float)(49.0/176.0),    A65 = (float)(-5103.0/18656.0);
    const float B1f = (float)(35.0/384.0),    B3f = (float)(500.0/1113.0),  B4f = (float)(125.0/192.0),
                B5f = (float)(-2187.0/6784.0),B6f = (float)(11.0/84.0);

    const float o1b = ob1[jo], o2b = ob2[jo], o3b = ob3[jo], o4b = ob4[jo];
    float dtv[4];
#pragma unroll
    for (int r = 0; r < 4; ++r) dtv[r] = dt_s[er4 * 4 + r];

#pragma unroll 1
    for (int st = 0; st < NST; ++st) {
#pragma unroll 1
        for (int stage = 0; stage < 6; ++stage) {
            const ushort_t* in0 = (stage == 0) ? YBF : YTB;
            f32x4 acc = mfma_layer<WBF>(in0, wsO1, oW1, lm, kb, jo);
            {
#pragma unroll
                for (int r = 0; r < 4; ++r)
                    T1B[midx(er4 * 4 + r, jo)] = f2bf(seluf_(acc[r] + o1b));
            }
            __syncthreads();
            acc = mfma_layer<WBF>(T1B, wsO2, oW2, lm, kb, jo);
            {
#pragma unroll
                for (int r = 0; r < 4; ++r)
                    T2B[midx(er4 * 4 + r, jo)] = f2bf(seluf_(acc[r] + o2b));
            }
            __syncthreads();
            acc = mfma_layer<WBF>(T2B, wsO3, oW3, lm, kb, jo);
            {
#pragma unroll
                for (int r = 0; r < 4; ++r)
                    T1B[midx(er4 * 4 + r, jo)] = f2bf(seluf_(acc[r] + o3b));
            }
            __syncthreads();
            acc = mfma_layer<WBF>(T1B, wsO4, oW4, lm, kb, jo);
            {
#pragma unroll
                for (int r = 0; r < 4; ++r) {
                    const int row = er4 * 4 + r;
                    const int ki = row * 256 + jo;
                    const float kc = acc[r] + o4b;
                    kstb[stage][ki] = f2bf(kc);
                    const float yv = h0[row][jo];
                    float sm;
                    switch (stage) {
                    case 0:
                        sm = A21 * kc;
                        break;
                    case 1: {
                        float k1v = bf2f(kstb[0][ki]);
                        sm = fmaf(A32, kc, A31 * k1v);
                        break; }
                    case 2: {
                        float k1v = bf2f(kstb[0][ki]), k2v = bf2f(kstb[1][ki]);
                        sm = fmaf(A43, kc, fmaf(A42, k2v, A41 * k1v));
                        break; }
                    case 3: {
                        float k1v = bf2f(kstb[0][ki]), k2v = bf2f(kstb[1][ki]);
                        float k3v = bf2f(kstb[2][ki]);
                        sm = fmaf(A54, kc, fmaf(A53, k3v, fmaf(A52, k2v, A51 * k1v)));
                        break; }
                    case 4: {
                        float k1v = bf2f(kstb[0][ki]), k2v = bf2f(kstb[1][ki]);
                        float k3v = bf2f(kstb[2][ki]), k4v = bf2f(kstb[3][ki]);
                        sm = fmaf(A65, kc, fmaf(A64, k4v,
                             fmaf(A63, k3v, fmaf(A62, k2v, A61 * k1v))));
                        break; }
                    default: {
                        float k1v = bf2f(kstb[0][ki]), k3v = bf2f(kstb[2][ki]);
                        float k4v = bf2f(kstb[3][ki]), k5v = bf2f(kstb[4][ki]);
                        sm = fmaf(B6f, kc, fmaf(B5f, k5v,
                             fmaf(B4f, k4v, fmaf(B3f, k3v, B1f * k1v))));
                        break; }
                    }
                    const float yn = fmaf(dtv[r], sm, yv);
                    if (stage < 5) {
                        YTB[midx(row, jo)] = f2bf(yn);
                    } else {
                        h0[row][jo] = yn;
                        YBF[midx(row, jo)] = f2bf(yn);
                    }
                }
            }
            __syncthreads();
        }
    }

    // ---- output head: 16 rows, 4 per pass ----
#pragma unroll 1
    for (int rp4 = 0; rp4 < 4; ++rp4) {
        const int R = rp4 * 4 + (tid >> 8);
        red[tid] = h0[R][t8] * outW[t8];
        __syncthreads();
        for (int sw = 128; sw > 0; sw >>= 1) {
            if (t8 < sw) red[tid] += red[tid + sw];
            __syncthreads();
        }
        if (t8 == 0) {
            float acc = red[tid] + outb[0];
#pragma unroll
            for (int mm = 0; mm < 4; ++mm) acc = fmaf(meta_s[R][mm], outW[HD + mm], acc);
            out[b0 + R] = acc;
        }
        __syncthreads();
    }
}

extern "C" void kernel_launch(void* const* d_in, const int* in_sizes, int n_in,
                              void* d_out, int out_size, void* d_ws, size_t ws_size,
                              hipStream_t stream) {
    const float* x    = (const float*)d_in[0];
    const float* meta = (const float*)d_in[1];
    const float* W_ih = (const float*)d_in[2];
    const float* W_hh = (const float*)d_in[3];
    const float* b_ih = (const float*)d_in[4];
    const float* b_hh = (const float*)d_in[5];
    const float* eW1  = (const float*)d_in[6];
    const float* eb1  = (const float*)d_in[7];
    const float* eW2  = (const float*)d_in[8];
    const float* eb2  = (const float*)d_in[9];
    const float* oW1  = (const float*)d_in[10];
    const float* ob1  = (const float*)d_in[11];
    const float* oW2  = (const float*)d_in[12];
    const float* ob2  = (const float*)d_in[13];
    const float* oW3  = (const float*)d_in[14];
    const float* ob3  = (const float*)d_in[15];
    const float* oW4  = (const float*)d_in[16];
    const float* ob4  = (const float*)d_in[17];
    const float* outW = (const float*)d_in[18];
    const float* outb = (const float*)d_in[19];

    const size_t need = (size_t)655360 * sizeof(ushort_t);   // 1.31 MB
    const bool wbf = (d_ws != nullptr) && (ws_size >= need);

    if (wbf) {
        cvt_k<<<2560, 256, 0, stream>>>(oW1, oW2, oW3, oW4, W_hh, eW1, eW2,
                                        (ushort_t*)d_ws);
        fused_kernel<1><<<BSZ / RB, TB, 0, stream>>>(x, meta, W_ih, W_hh, b_ih, b_hh,
                                                     eW1, eb1, eW2, eb2,
                                                     oW1, ob1, oW2, ob2, oW3, ob3, oW4, ob4,
                                                     outW, outb, (const ushort_t*)d_ws,
                                                     (float*)d_out);
    } else {
        fused_kernel<0><<<BSZ / RB, TB, 0, stream>>>(x, meta, W_ih, W_hh, b_ih, b_hh,
                                                     eW1, eb1, eW2, eb2,
                                                     oW1, ob1, oW2, ob2, oW3, ob3, oW4, ob4,
                                                     outW, outb, (const ushort_t*)nullptr,
                                                     (float*)d_out);
    }
}

// Round 21
// 1738.454 us; speedup vs baseline: 4.2866x; 1.2702x over previous
//
#include <hip/hip_runtime.h>
#include <math.h>

#define HD   256
#define RB   16     // batch rows per block == MFMA tile M -> grid 128
#define TB   1024   // 16 waves
#define TT   64
#define NST  32
#define BSZ  2048

typedef __attribute__((ext_vector_type(8))) short short8;
typedef __attribute__((ext_vector_type(4))) float f32x4;
typedef unsigned short ushort_t;

// ---------------- math helpers ----------------
__device__ __forceinline__ float sigmoidf_(float x) {
    return 1.0f / (1.0f + __expf(-x));
}
__device__ __forceinline__ float tanhf_(float x) {
    float e = __expf(2.0f * x);
    return 1.0f - 2.0f / (e + 1.0f);
}
__device__ __forceinline__ float seluf_(float x) {
    const float a = 1.6732632423543772f, s = 1.0507009873554805f;
    return x > 0.0f ? s * x : s * a * (__expf(x) - 1.0f);
}
__device__ __forceinline__ float erfinvf_(float x) {
    float w = -log1pf(-x * x);
    float p;
    if (w < 5.0f) {
        w -= 2.5f;
        p = 2.81022636e-08f;
        p = fmaf(p, w, 3.43273939e-07f);
        p = fmaf(p, w, -3.5233877e-06f);
        p = fmaf(p, w, -4.39150654e-06f);
        p = fmaf(p, w, 0.00021858087f);
        p = fmaf(p, w, -0.00125372503f);
        p = fmaf(p, w, -0.00417768164f);
        p = fmaf(p, w, 0.246640727f);
        p = fmaf(p, w, 1.50140941f);
    } else {
        w = sqrtf(w) - 3.0f;
        p = -0.000200214257f;
        p = fmaf(p, w, 0.000100950558f);
        p = fmaf(p, w, 0.00134934322f);
        p = fmaf(p, w, -0.00367342844f);
        p = fmaf(p, w, 0.00573950773f);
        p = fmaf(p, w, -0.0076224613f);
        p = fmaf(p, w, 0.00943887047f);
        p = fmaf(p, w, 1.00167406f);
        p = fmaf(p, w, 2.83297682f);
    }
    return p * x;
}

#define TF_ROUND(x0, x1, R) { x0 += x1; x1 = (x1 << (R)) | (x1 >> (32 - (R))); x1 ^= x0; }

__device__ __forceinline__ void threefry_(unsigned c0, unsigned c1, unsigned& r0, unsigned& r1) {
    const unsigned ks0 = 0u, ks1 = 42u, ks2 = 0x1BD11BDAu ^ 0u ^ 42u;
    unsigned x0 = c0 + ks0, x1 = c1 + ks1;
    TF_ROUND(x0,x1,13) TF_ROUND(x0,x1,15) TF_ROUND(x0,x1,26) TF_ROUND(x0,x1,6)
    x0 += ks1; x1 += ks2 + 1u;
    TF_ROUND(x0,x1,17) TF_ROUND(x0,x1,29) TF_ROUND(x0,x1,16) TF_ROUND(x0,x1,24)
    x0 += ks2; x1 += ks0 + 2u;
    TF_ROUND(x0,x1,13) TF_ROUND(x0,x1,15) TF_ROUND(x0,x1,26) TF_ROUND(x0,x1,6)
    x0 += ks0; x1 += ks1 + 3u;
    TF_ROUND(x0,x1,17) TF_ROUND(x0,x1,29) TF_ROUND(x0,x1,16) TF_ROUND(x0,x1,24)
    x0 += ks1; x1 += ks2 + 4u;
    TF_ROUND(x0,x1,13) TF_ROUND(x0,x1,15) TF_ROUND(x0,x1,26) TF_ROUND(x0,x1,6)
    x0 += ks2; x1 += ks0 + 5u;
    r0 = x0; r1 = x1;
}

// eps[i]: bits = o0 ^ o1 of threefry2x32(key(0,42), (0, i))  [verified round 5]
__device__ __forceinline__ float jax_normal_(unsigned i) {
    unsigned o0, o1;
    threefry_(0u, i, o0, o1);
    unsigned bits = o0 ^ o1;
    unsigned fb = (bits >> 9) | 0x3F800000u;
    float f = __uint_as_float(fb) - 1.0f;
    const float lo = -0.99999994f;
    float u = f * 2.0f + lo;
    u = fmaxf(lo, u);
    return 1.41421356237f * erfinvf_(u);
}

// fp32 <-> bf16
__device__ __forceinline__ ushort_t f2bf(float f) {
    unsigned u = __float_as_uint(f);
    return (ushort_t)((u + 0x7FFFu + ((u >> 16) & 1u)) >> 16);
}
__device__ __forceinline__ float bf2f(ushort_t u) {
    return __uint_as_float(((unsigned)u) << 16);
}

// swizzled bf16 mirror index (ushort units): row stride 256, 16B-chunk XOR swizzle
__device__ __forceinline__ int midx(int row, int k) {
    int chunk = k >> 3;
    return row * 256 + (((chunk ^ (row & 7)) << 3) | (k & 7));
}

// fp32-row fallback B fragment (WBF=0 path only)
__device__ __forceinline__ short8 ldw_f32(const float* __restrict__ Wf, int row, int k0) {
    const float4 w0 = *(const float4*)(Wf + (size_t)row * 256 + k0);
    const float4 w1 = *(const float4*)(Wf + (size_t)row * 256 + k0 + 4);
    union { ushort_t u[8]; short8 v; } bb;
    bb.u[0] = f2bf(w0.x); bb.u[1] = f2bf(w0.y); bb.u[2] = f2bf(w0.z); bb.u[3] = f2bf(w0.w);
    bb.u[4] = f2bf(w1.x); bb.u[5] = f2bf(w1.y); bb.u[6] = f2bf(w1.z); bb.u[7] = f2bf(w1.w);
    return bb.v;
}

// MFMA 256->256 layer slice.
// WBF=1: B from FRAGMENT-MAJOR packed blob -- wave w, lane l, slice kt reads
//        Wp[((w*8+kt)*64 + l)*8 .. +8): 64 lanes x 16B CONTIGUOUS (one 1KB burst).
// WBF=0: fallback row-major fp32 reads (slow, correct).
template<int WBF>
__device__ __forceinline__ f32x4 mfma_layer(const ushort_t* __restrict__ inbf,
                                            const ushort_t* __restrict__ Wp,
                                            const float* __restrict__ Wf,
                                            const int lm, const int kb,
                                            const int wv, const int l, const int jo)
{
    f32x4 acc = {0.f, 0.f, 0.f, 0.f};
    const ushort_t* wpl = Wp + (((size_t)wv * 8) * 64 + l) * 8;
#pragma unroll
    for (int kt = 0; kt < 8; ++kt) {
        const int k0 = kt * 32 + kb * 8;
        short8 a = *(const short8*)(inbf + midx(lm, k0));
        short8 b;
        if (WBF) b = *(const short8*)(wpl + kt * 512);
        else     b = ldw_f32(Wf, jo, k0);
        acc = __builtin_amdgcn_mfma_f32_16x16x32_bf16(a, b, acc, 0, 0, 0);
    }
    return acc;
}

// ---------------- weight bf16 PACKED conversion prepass ----------------
// Packed layout per 256x256 matrix: dst[((nt*8+kt)*64 + l)*8 + e] =
//   src[nt*16 + (l&15)][kt*32 + (l>>4)*8 + e]
// Matrices (65536 elems each): 0..3 O1..O4 | 4..6 Whh r/z/n | 7 E1 | 8 E2-mean | 9 E2-std
__global__ void cvt_k(const float* __restrict__ o1, const float* __restrict__ o2,
                      const float* __restrict__ o3, const float* __restrict__ o4,
                      const float* __restrict__ whh, const float* __restrict__ e1,
                      const float* __restrict__ e2, ushort_t* __restrict__ out) {
    int i = blockIdx.x * blockDim.x + threadIdx.x;
    if (i >= 655360) return;
    int m = i >> 16, r = i & 65535;
    const float* src;
    switch (m) {
    case 0: src = o1; break;
    case 1: src = o2; break;
    case 2: src = o3; break;
    case 3: src = o4; break;
    case 4: src = whh; break;
    case 5: src = whh + 65536; break;
    case 6: src = whh + 131072; break;
    case 7: src = e1; break;
    case 8: src = e2; break;
    default: src = e2 + 65536; break;
    }
    int e  = r & 7;
    int l  = (r >> 3) & 63;
    int kt = (r >> 9) & 7;
    int nt = r >> 12;
    int srow = nt * 16 + (l & 15);
    int sk   = kt * 32 + (l >> 4) * 8 + e;
    out[i] = f2bf(src[srow * 256 + sk]);
}

// ---------------- fused pipeline kernel ----------------
// RB=16 full tiles, grid 128; launch_bounds(TB,4)=128 unified regs, inline B -> no spill.
// Packed fragment-major weights: each B-load = one contiguous 1KB wave burst.
template<int WBF>
__global__ __launch_bounds__(TB, 4) void fused_kernel(
    const float* __restrict__ x,
    const float* __restrict__ meta,
    const float* __restrict__ W_ih,
    const float* __restrict__ W_hh,
    const float* __restrict__ b_ih,
    const float* __restrict__ b_hh,
    const float* __restrict__ eW1,
    const float* __restrict__ eb1,
    const float* __restrict__ eW2,
    const float* __restrict__ eb2,
    const float* __restrict__ oW1, const float* __restrict__ ob1,
    const float* __restrict__ oW2, const float* __restrict__ ob2,
    const float* __restrict__ oW3, const float* __restrict__ ob3,
    const float* __restrict__ oW4, const float* __restrict__ ob4,
    const float* __restrict__ outW,
    const float* __restrict__ outb,
    const ushort_t* __restrict__ wsbf,
    float* __restrict__ out)
{
    const int tid = threadIdx.x;
    const int t8  = tid & 255;
    const int l   = tid & 63;
    const int wv  = tid >> 6;            // wave == n-tile
    const int lm  = l & 15;
    const int kb  = l >> 4;
    const int jo  = wv * 16 + lm;        // owned output col
    const int er4 = l >> 4;              // epilogue rows er4*4 + r
    const int b0  = blockIdx.x * RB;

    __shared__ float h0[RB][HD];                        // 16 KB
    __shared__ float xall[RB][TT * 4];                  // 16 KB
    __shared__ float red[TB];                           // 4 KB
    __shared__ __align__(16) ushort_t mir[4][RB][256];  // 32 KB
    __shared__ ushort_t kstb[6][RB * 256];              // 48 KB
    __shared__ float meta_s[RB][4];
    __shared__ float dt_s[RB];

    ushort_t* YBF = &mir[0][0][0];
    ushort_t* YTB = &mir[1][0][0];
    ushort_t* T1B = &mir[2][0][0];
    ushort_t* T2B = &mir[3][0][0];
    const ushort_t* wsO1  = wsbf;
    const ushort_t* wsO2  = wsbf + 65536;
    const ushort_t* wsO3  = wsbf + 131072;
    const ushort_t* wsO4  = wsbf + 196608;
    const ushort_t* wsWr  = wsbf + 262144;
    const ushort_t* wsWz  = wsbf + 327680;
    const ushort_t* wsWn  = wsbf + 393216;
    const ushort_t* wsE1  = wsbf + 458752;
    const ushort_t* wsE2m = wsbf + 524288;
    const ushort_t* wsE2s = wsbf + 589824;

    // ---- stage x, meta; zero h0 and mirrors ----
#pragma unroll
    for (int i = 0; i < 4; ++i) {
        int idx = tid + i * TB;              // 0..4095
        int r = idx >> 8, c = idx & 255;
        xall[r][c] = x[(size_t)(b0 + r) * 256 + c];
        h0[r][c] = 0.0f;
    }
    if (tid < RB * 4) { int r = tid >> 2, mm = tid & 3; meta_s[r][mm] = meta[(b0 + r) * 4 + mm]; }
    {
        unsigned* mz = (unsigned*)&mir[0][0][0];
#pragma unroll
        for (int i = 0; i < 8; ++i) mz[tid + i * TB] = 0u;
    }
    __syncthreads();
    if (tid < RB) dt_s[tid] = (xall[tid][TT * 4 - 4] - xall[tid][0]) * (1.0f / (float)NST);

    // ---- GRU per-lane x-side constants for owned col jo ----
    float wxr[4], wxz[4], wxn[4];
#pragma unroll
    for (int d = 0; d < 4; ++d) {
        wxr[d] = W_ih[(size_t)jo * 8 + d];
        wxz[d] = W_ih[(size_t)(jo + 256) * 8 + d];
        wxn[d] = W_ih[(size_t)(jo + 512) * 8 + d];
    }
    float base_r[4], base_z[4], base_xn[4];
    {
        float mwr[4], mwz[4], mwn[4];
#pragma unroll
        for (int mm = 0; mm < 4; ++mm) {
            mwr[mm] = W_ih[(size_t)jo * 8 + 4 + mm];
            mwz[mm] = W_ih[(size_t)(jo + 256) * 8 + 4 + mm];
            mwn[mm] = W_ih[(size_t)(jo + 512) * 8 + 4 + mm];
        }
        const float bir = b_ih[jo], biz = b_ih[jo + 256], bin_ = b_ih[jo + 512];
        const float bhr = b_hh[jo], bhz = b_hh[jo + 256];
#pragma unroll
        for (int r = 0; r < 4; ++r) {
            const int R = er4 * 4 + r;
            float sr = bir + bhr, sz = biz + bhz, sn = bin_;
#pragma unroll
            for (int mm = 0; mm < 4; ++mm) {
                float mv = meta_s[R][mm];
                sr = fmaf(mv, mwr[mm], sr);
                sz = fmaf(mv, mwz[mm], sz);
                sn = fmaf(mv, mwn[mm], sn);
            }
            base_r[r] = sr; base_z[r] = sz; base_xn[r] = sn;
        }
    }
    const float bhn = b_hh[512 + jo];

    // ---- GRU: 64 steps, MFMA bf16 packed-B, mirror ping-pong, ONE barrier/step ----
    const ushort_t* wrl = wsWr + (((size_t)wv * 8) * 64 + l) * 8;
    const ushort_t* wzl = wsWz + (((size_t)wv * 8) * 64 + l) * 8;
    const ushort_t* wnl = wsWn + (((size_t)wv * 8) * 64 + l) * 8;
    int p = 0;
#pragma unroll 1
    for (int t = 0; t < TT; ++t) {
        const ushort_t* YHp = &mir[p][0][0];
        f32x4 aR = {0.f,0.f,0.f,0.f}, aZ = {0.f,0.f,0.f,0.f}, aN = {0.f,0.f,0.f,0.f};
#pragma unroll 2
        for (int kt = 0; kt < 8; ++kt) {
            const int k0 = kt * 32 + kb * 8;
            short8 a = *(const short8*)(YHp + midx(lm, k0));
            short8 b;
            if (WBF) b = *(const short8*)(wrl + kt * 512);
            else     b = ldw_f32(W_hh, jo, k0);
            aR = __builtin_amdgcn_mfma_f32_16x16x32_bf16(a, b, aR, 0, 0, 0);
            if (WBF) b = *(const short8*)(wzl + kt * 512);
            else     b = ldw_f32(W_hh, jo + 256, k0);
            aZ = __builtin_amdgcn_mfma_f32_16x16x32_bf16(a, b, aZ, 0, 0, 0);
            if (WBF) b = *(const short8*)(wnl + kt * 512);
            else     b = ldw_f32(W_hh, jo + 512, k0);
            aN = __builtin_amdgcn_mfma_f32_16x16x32_bf16(a, b, aN, 0, 0, 0);
        }
        {
            ushort_t* YHn = &mir[p ^ 1][0][0];
#pragma unroll
            for (int r = 0; r < 4; ++r) {
                const int R = er4 * 4 + r;
                float xr = base_r[r], xz = base_z[r], xn = base_xn[r];
#pragma unroll
                for (int d = 0; d < 4; ++d) {
                    float xv = xall[R][t * 4 + d];
                    xr = fmaf(xv, wxr[d], xr);
                    xz = fmaf(xv, wxz[d], xz);
                    xn = fmaf(xv, wxn[d], xn);
                }
                float rg = sigmoidf_(xr + aR[r]);
                float zg = sigmoidf_(xz + aZ[r]);
                float ng = tanhf_(fmaf(rg, aN[r] + bhn, xn));
                float hp = h0[R][jo];
                float hnew = fmaf(zg, hp - ng, ng);
                h0[R][jo] = hnew;
                YHn[midx(R, jo)] = f2bf(hnew);
            }
        }
        __syncthreads();
        p ^= 1;
    }

    // ---- encoder (MFMA bf16 packed): relu(h@E1+b1); mean/std; sample y0 ----
    {
        f32x4 acc = mfma_layer<WBF>(YBF, wsE1, eW1, lm, kb, wv, l, jo);
        {
            const float eb1j = eb1[jo];
#pragma unroll
            for (int r = 0; r < 4; ++r)
                T1B[midx(er4 * 4 + r, jo)] = f2bf(fmaxf(acc[r] + eb1j, 0.0f));
        }
        __syncthreads();

        f32x4 aM = mfma_layer<WBF>(T1B, wsE2m, eW2, lm, kb, wv, l, jo);
        f32x4 aS = mfma_layer<WBF>(T1B, wsE2s, eW2 + 65536, lm, kb, wv, l, jo);
        {
            const float bm = eb2[jo], bs = eb2[256 + jo];
#pragma unroll
            for (int r = 0; r < 4; ++r) {
                const int row = er4 * 4 + r;
                float e = jax_normal_((unsigned)((b0 + row) * HD + jo));
                float y0v = fmaf(e, aS[r] + bs, aM[r] + bm);
                h0[row][jo] = y0v;
                YBF[midx(row, jo)] = f2bf(y0v);
            }
        }
        __syncthreads();
    }

    // ---- dopri5: MFMA bf16 packed-B ODE; k's in bf16 LDS ----
    const float A21 = (float)(1.0/5.0);
    const float A31 = (float)(3.0/40.0),      A32 = (float)(9.0/40.0);
    const float A41 = (float)(44.0/45.0),     A42 = (float)(-56.0/15.0),    A43 = (float)(32.0/9.0);
    const float A51 = (float)(19372.0/6561.0),A52 = (float)(-25360.0/2187.0),
                A53 = (float)(64448.0/6561.0),A54 = (float)(-212.0/729.0);
    const float A61 = (float)(9017.0/3168.0), A62 = (float)(-355.0/33.0),
                A63 = (float)(46732.0/5247.0),A64 = (float)(49.0/176.0),    A65 = (float)(-5103.0/18656.0);
    const float B1f = (float)(35.0/384.0),    B3f = (float)(500.0/1113.0),  B4f = (float)(125.0/192.0),
                B5f = (float)(-2187.0/6784.0),B6f = (float)(11.0/84.0);

    const float o1b = ob1[jo], o2b = ob2[jo], o3b = ob3[jo], o4b = ob4[jo];
    float dtv[4];
#pragma unroll
    for (int r = 0; r < 4; ++r) dtv[r] = dt_s[er4 * 4 + r];

#pragma unroll 1
    for (int st = 0; st < NST; ++st) {
#pragma unroll 1
        for (int stage = 0; stage < 6; ++stage) {
            const ushort_t* in0 = (stage == 0) ? YBF : YTB;
            f32x4 acc = mfma_layer<WBF>(in0, wsO1, oW1, lm, kb, wv, l, jo);
            {
#pragma unroll
                for (int r = 0; r < 4; ++r)
                    T1B[midx(er4 * 4 + r, jo)] = f2bf(seluf_(acc[r] + o1b));
            }
            __syncthreads();
            acc = mfma_layer<WBF>(T1B, wsO2, oW2, lm, kb, wv, l, jo);
            {
#pragma unroll
                for (int r = 0; r < 4; ++r)
                    T2B[midx(er4 * 4 + r, jo)] = f2bf(seluf_(acc[r] + o2b));
            }
            __syncthreads();
            acc = mfma_layer<WBF>(T2B, wsO3, oW3, lm, kb, wv, l, jo);
            {
#pragma unroll
                for (int r = 0; r < 4; ++r)
                    T1B[midx(er4 * 4 + r, jo)] = f2bf(seluf_(acc[r] + o3b));
            }
            __syncthreads();
            acc = mfma_layer<WBF>(T1B, wsO4, oW4, lm, kb, wv, l, jo);
            {
#pragma unroll
                for (int r = 0; r < 4; ++r) {
                    const int row = er4 * 4 + r;
                    const int ki = row * 256 + jo;
                    const float kc = acc[r] + o4b;
                    kstb[stage][ki] = f2bf(kc);
                    const float yv = h0[row][jo];
                    float sm;
                    switch (stage) {
                    case 0:
                        sm = A21 * kc;
                        break;
                    case 1: {
                        float k1v = bf2f(kstb[0][ki]);
                        sm = fmaf(A32, kc, A31 * k1v);
                        break; }
                    case 2: {
                        float k1v = bf2f(kstb[0][ki]), k2v = bf2f(kstb[1][ki]);
                        sm = fmaf(A43, kc, fmaf(A42, k2v, A41 * k1v));
                        break; }
                    case 3: {
                        float k1v = bf2f(kstb[0][ki]), k2v = bf2f(kstb[1][ki]);
                        float k3v = bf2f(kstb[2][ki]);
                        sm = fmaf(A54, kc, fmaf(A53, k3v, fmaf(A52, k2v, A51 * k1v)));
                        break; }
                    case 4: {
                        float k1v = bf2f(kstb[0][ki]), k2v = bf2f(kstb[1][ki]);
                        float k3v = bf2f(kstb[2][ki]), k4v = bf2f(kstb[3][ki]);
                        sm = fmaf(A65, kc, fmaf(A64, k4v,
                             fmaf(A63, k3v, fmaf(A62, k2v, A61 * k1v))));
                        break; }
                    default: {
                        float k1v = bf2f(kstb[0][ki]), k3v = bf2f(kstb[2][ki]);
                        float k4v = bf2f(kstb[3][ki]), k5v = bf2f(kstb[4][ki]);
                        sm = fmaf(B6f, kc, fmaf(B5f, k5v,
                             fmaf(B4f, k4v, fmaf(B3f, k3v, B1f * k1v))));
                        break; }
                    }
                    const float yn = fmaf(dtv[r], sm, yv);
                    if (stage < 5) {
                        YTB[midx(row, jo)] = f2bf(yn);
                    } else {
                        h0[row][jo] = yn;
                        YBF[midx(row, jo)] = f2bf(yn);
                    }
                }
            }
            __syncthreads();
        }
    }

    // ---- output head: 16 rows, 4 per pass ----
#pragma unroll 1
    for (int rp4 = 0; rp4 < 4; ++rp4) {
        const int R = rp4 * 4 + (tid >> 8);
        red[tid] = h0[R][t8] * outW[t8];
        __syncthreads();
        for (int sw = 128; sw > 0; sw >>= 1) {
            if (t8 < sw) red[tid] += red[tid + sw];
            __syncthreads();
        }
        if (t8 == 0) {
            float acc = red[tid] + outb[0];
#pragma unroll
            for (int mm = 0; mm < 4; ++mm) acc = fmaf(meta_s[R][mm], outW[HD + mm], acc);
            out[b0 + R] = acc;
        }
        __syncthreads();
    }
}

extern "C" void kernel_launch(void* const* d_in, const int* in_sizes, int n_in,
                              void* d_out, int out_size, void* d_ws, size_t ws_size,
                              hipStream_t stream) {
    const float* x    = (const float*)d_in[0];
    const float* meta = (const float*)d_in[1];
    const float* W_ih = (const float*)d_in[2];
    const float* W_hh = (const float*)d_in[3];
    const float* b_ih = (const float*)d_in[4];
    const float* b_hh = (const float*)d_in[5];
    const float* eW1  = (const float*)d_in[6];
    const float* eb1  = (const float*)d_in[7];
    const float* eW2  = (const float*)d_in[8];
    const float* eb2  = (const float*)d_in[9];
    const float* oW1  = (const float*)d_in[10];
    const float* ob1  = (const float*)d_in[11];
    const float* oW2  = (const float*)d_in[12];
    const float* ob2  = (const float*)d_in[13];
    const float* oW3  = (const float*)d_in[14];
    const float* ob3  = (const float*)d_in[15];
    const float* oW4  = (const float*)d_in[16];
    const float* ob4  = (const float*)d_in[17];
    const float* outW = (const float*)d_in[18];
    const float* outb = (const float*)d_in[19];

    const size_t need = (size_t)655360 * sizeof(ushort_t);   // 1.31 MB
    const bool wbf = (d_ws != nullptr) && (ws_size >= need);

    if (wbf) {
        cvt_k<<<2560, 256, 0, stream>>>(oW1, oW2, oW3, oW4, W_hh, eW1, eW2,
                                        (ushort_t*)d_ws);
        fused_kernel<1><<<BSZ / RB, TB, 0, stream>>>(x, meta, W_ih, W_hh, b_ih, b_hh,
                                                     eW1, eb1, eW2, eb2,
                                                     oW1, ob1, oW2, ob2, oW3, ob3, oW4, ob4,
                                                     outW, outb, (const ushort_t*)d_ws,
                                                     (float*)d_out);
    } else {
        fused_kernel<0><<<BSZ / RB, TB, 0, stream>>>(x, meta, W_ih, W_hh, b_ih, b_hh,
                                                     eW1, eb1, eW2, eb2,
                                                     oW1, ob1, oW2, ob2, oW3, ob3, oW4, ob4,
                                                     outW, outb, (const ushort_t*)nullptr,
                                                     (float*)d_out);
    }
}